// Round 4
// baseline (134.120 us; speedup 1.0000x reference)
//
#include <hip/hip_runtime.h>
#include <math.h>

// Deepmd angular descriptor, f32 in / f32 out. B=8, N=4096, M=96, OUT_W=384.
//
// R19: "streaming drift" — no LDS, no barriers, self-paced waves.
// Evidence chain: R15(32w/CU)==R16(16w/CU,depth-1)==34us; R18(gll16+counted
// vmcnt+phase barriers)=40us; R17 cold(34us) = warm(15.4us) + HBM-read
// (18.6us) EXACTLY additive; Little's law rules out in-flight-bytes as the
// limit (60KB/CU supports ~36TB/s, we see 3.3). Only surviving model:
// chip-wide CONVOY — the post-staging __syncthreads aligns all waves, and
// identical iteration lengths keep the whole grid oscillating in lockstep
// between an all-waves load burst (queue floods) and an all-waves compute
// phase (memory idles). Fix: remove the position LDS table (the only reason
// a barrier exists) — positions are 48KB/batch, L1/L2-hot, gathered per-lane
// from global. Each wave owns 8 consecutive pairs, ring-3 register pipeline
// (2-3 iterations of stream loads always in flight, fully unrolled -> static
// indexing), no sync anywhere -> wave phases decohere like the 6.3TB/s copy
// ubench. Consume machinery (ballot-rank + register merge + b128/b64 stores)
// is byte-identical to R15's proven version.
#define M_NB   96
#define OUT_W  384
#define WAVES  8                    // 512 threads/block
#define PAIRS_PW 8                  // 8 pairs = 16 rows per wave
#define LOWM   0x00000000FFFFFFFFull
#define HIGHM  0xFFFFFFFF00000000ull

struct Pref {
    int    j0, j1, j2;
    float  m0, m1, m2;
    float3 o0, o1, o2;
};

__device__ __forceinline__ void ldpref(Pref& P,
                                       const int* __restrict__ neighbors,
                                       const float* __restrict__ mask,
                                       const float* __restrict__ offsets,
                                       long e0)
{
    const long e1 = e0 + 64, e2 = e0 + 128;
    P.j0 = neighbors[e0]; P.j1 = neighbors[e1]; P.j2 = neighbors[e2];
    P.m0 = mask[e0];      P.m1 = mask[e1];      P.m2 = mask[e2];
    P.o0 = *(const float3*)(offsets + e0 * 3);
    P.o1 = *(const float3*)(offsets + e1 * 3);
    P.o2 = *(const float3*)(offsets + e2 * 3);
}

// fold one item (row floats [base,base+3)) into this lane's output slots:
// float4 owns [4*lane,4*lane+4), float2 owns [256+2*lane,256+2*lane+2)
__device__ __forceinline__ void merge3(float4& a4, float2& a2, int base,
                                       float v0, float v1, float v2, int lane)
{
    const int f4lo = 4 * lane;
    const int f2lo = 256 + 2 * lane;
    const float v[3] = {v0, v1, v2};
    #pragma unroll
    for (int t = 0; t < 3; ++t) {
        const int idx = base + t;
        if      (idx == f4lo)     a4.x = v[t];
        else if (idx == f4lo + 1) a4.y = v[t];
        else if (idx == f4lo + 2) a4.z = v[t];
        else if (idx == f4lo + 3) a4.w = v[t];
        else if (idx == f2lo)     a2.x = v[t];
        else if (idx == f2lo + 1) a2.y = v[t];
    }
}

// consume one pair (rows q0, q0+1) from prefetched stream regs; positions
// gathered per-lane from global (L1/L2-hot 48KB/batch table).
__device__ __forceinline__ void consume_pair(
    const Pref& P, int q0, int nbase,
    const float* __restrict__ posg, float* __restrict__ out,
    float c00, float c01, float c02, float c10, float c11, float c12,
    float c20, float c21, float c22, int lane)
{
    const int nn0 = q0 - nbase;
    const float3 pi0 = *(const float3*)(posg + 3 * nn0);   // uniform
    const float3 pi1 = *(const float3*)(posg + 3 * (nn0 + 1));
    const float3 pj0 = *(const float3*)(posg + 3 * P.j0);  // random gathers
    const float3 pj1 = *(const float3*)(posg + 3 * P.j1);
    const float3 pj2 = *(const float3*)(posg + 3 * P.j2);
    const float3 pa  = (lane < 32) ? pi0 : pi1;   // item1's own atom

    // ---- cut per item (w = cut * dis_vec stored in-place) ----
    float w0x = pj0.x - pi0.x + P.o0.x * c00 + P.o0.y * c10 + P.o0.z * c20;
    float w0y = pj0.y - pi0.y + P.o0.x * c01 + P.o0.y * c11 + P.o0.z * c21;
    float w0z = pj0.z - pi0.z + P.o0.x * c02 + P.o0.y * c12 + P.o0.z * c22;
    float d   = sqrtf(w0x * w0x + w0y * w0y + w0z * w0z + 1e-12f);
    float c0v = 0.f;
    if (P.m0 != 0.f && d < 6.f)
        c0v = 0.5f * (__cosf(d * 0.52359877559829887f) + 1.f) / d;
    w0x *= c0v; w0y *= c0v; w0z *= c0v;

    float w1x = pj1.x - pa.x + P.o1.x * c00 + P.o1.y * c10 + P.o1.z * c20;
    float w1y = pj1.y - pa.y + P.o1.x * c01 + P.o1.y * c11 + P.o1.z * c21;
    float w1z = pj1.z - pa.z + P.o1.x * c02 + P.o1.y * c12 + P.o1.z * c22;
    d = sqrtf(w1x * w1x + w1y * w1y + w1z * w1z + 1e-12f);
    float c1v = 0.f;
    if (P.m1 != 0.f && d < 6.f)
        c1v = 0.5f * (__cosf(d * 0.52359877559829887f) + 1.f) / d;
    w1x *= c1v; w1y *= c1v; w1z *= c1v;

    float w2x = pj2.x - pi1.x + P.o2.x * c00 + P.o2.y * c10 + P.o2.z * c20;
    float w2y = pj2.y - pi1.y + P.o2.x * c01 + P.o2.y * c11 + P.o2.z * c21;
    float w2z = pj2.z - pi1.z + P.o2.x * c02 + P.o2.y * c12 + P.o2.z * c22;
    d = sqrtf(w2x * w2x + w2y * w2y + w2z * w2z + 1e-12f);
    float c2v = 0.f;
    if (P.m2 != 0.f && d < 6.f)
        c2v = 0.5f * (__cosf(d * 0.52359877559829887f) + 1.f) / d;
    w2x *= c2v; w2y *= c2v; w2z *= c2v;

    // ---- row0: rank + register merge ----
    // rank(m) = #{k: cut_k > cut_m} + #{k<m: cut_k == cut_m}
    float4 a4 = make_float4(0.f, 0.f, 0.f, 0.f);
    float2 a2 = make_float2(0.f, 0.f);
    unsigned long long t = __ballot(c0v != 0.f);
    while (t) {                                  // item m = s (c0 owner)
        const int s = (int)__builtin_ctzll(t); t &= t - 1;
        const float c = __shfl(c0v, s);
        const int rank = __popcll(__ballot(c0v > c))
                       + __popcll(__ballot(c1v > c) & LOWM)
                       + __popcll(__ballot(c0v == c) & ((1ull << s) - 1ull));
        merge3(a4, a2, 3 * rank,
               __shfl(w0x, s), __shfl(w0y, s), __shfl(w0z, s), lane);
    }
    t = __ballot(c1v != 0.f) & LOWM;
    while (t) {                                  // item m = 64+s (c1 low)
        const int s = (int)__builtin_ctzll(t); t &= t - 1;
        const float c = __shfl(c1v, s);
        const int rank = __popcll(__ballot(c0v > c))
                       + __popcll(__ballot(c1v > c) & LOWM)
                       + __popcll(__ballot(c0v == c))
                       + __popcll(__ballot(c1v == c) & LOWM & ((1ull << s) - 1ull));
        merge3(a4, a2, 3 * rank,
               __shfl(w1x, s), __shfl(w1y, s), __shfl(w1z, s), lane);
    }
    float* row0 = out + (size_t)q0 * OUT_W;
    ((float4*)row0)[lane] = a4;
    ((float2*)(row0 + 256))[lane] = a2;

    // ---- row1: rank + register merge ----
    float4 b4 = make_float4(0.f, 0.f, 0.f, 0.f);
    float2 b2 = make_float2(0.f, 0.f);
    t = __ballot(c1v != 0.f) & HIGHM;
    while (t) {                                  // item m = s-32 (c1 high)
        const int s = (int)__builtin_ctzll(t); t &= t - 1;
        const float c = __shfl(c1v, s);
        const int rank = __popcll(__ballot(c1v > c) & HIGHM)
                       + __popcll(__ballot(c2v > c))
                       + __popcll(__ballot(c1v == c) & HIGHM & ((1ull << s) - 1ull));
        merge3(b4, b2, 3 * rank,
               __shfl(w1x, s), __shfl(w1y, s), __shfl(w1z, s), lane);
    }
    t = __ballot(c2v != 0.f);
    while (t) {                                  // item m = 32+s (c2 owner)
        const int s = (int)__builtin_ctzll(t); t &= t - 1;
        const float c = __shfl(c2v, s);
        const int rank = __popcll(__ballot(c1v > c) & HIGHM)
                       + __popcll(__ballot(c2v > c))
                       + __popcll(__ballot(c1v == c) & HIGHM)
                       + __popcll(__ballot(c2v == c) & ((1ull << s) - 1ull));
        merge3(b4, b2, 3 * rank,
               __shfl(w2x, s), __shfl(w2y, s), __shfl(w2z, s), lane);
    }
    float* row1 = out + (size_t)(q0 + 1) * OUT_W;
    ((float4*)row1)[lane] = b4;
    ((float2*)(row1 + 256))[lane] = b2;
}

__global__ __launch_bounds__(64 * WAVES, 4) void deepmd_angular_kernel(
    const float* __restrict__ positions,  // [B,N,3]
    const float* __restrict__ cell,       // [B,3,3]
    const float* __restrict__ offsets,    // [B,N,M,3]
    const float* __restrict__ mask,       // [B,N,M]
    const int*   __restrict__ neighbors,  // [B,N,M]
    float*       __restrict__ out,        // [B,N,OUT_W]
    int N)
{
    const int tid  = threadIdx.x;
    const int wv   = tid >> 6;
    const int lane = tid & 63;

    const int rows_pb = WAVES * PAIRS_PW * 2;            // 128 rows per block
    const int row0    = blockIdx.x * rows_pb;
    const int b       = row0 / N;                        // uniform (128 | N)
    const int nbase   = b * N;

    const float* posg = positions + (size_t)b * N * 3;

    const float* cb = cell + (size_t)b * 9;              // uniform scalar loads
    const float c00 = cb[0], c01 = cb[1], c02 = cb[2];
    const float c10 = cb[3], c11 = cb[4], c12 = cb[5];
    const float c20 = cb[6], c21 = cb[7], c22 = cb[8];

    const int  wrow  = row0 + wv * (PAIRS_PW * 2);       // wave's first row
    const long wbase = (long)wrow * M_NB;                // contiguous 1536 elems

    // ---- ring-3 register pipeline over this wave's 8 pairs ----
    Pref PA, PB, PC;
    ldpref(PA, neighbors, mask, offsets, wbase + 0L * 192 + lane);
    ldpref(PB, neighbors, mask, offsets, wbase + 1L * 192 + lane);
    ldpref(PC, neighbors, mask, offsets, wbase + 2L * 192 + lane);

    #pragma unroll
    for (int k = 0; k < PAIRS_PW; ++k) {
        Pref& cur = (k % 3 == 0) ? PA : ((k % 3 == 1) ? PB : PC);
        consume_pair(cur, wrow + 2 * k, nbase, posg, out,
                     c00, c01, c02, c10, c11, c12, c20, c21, c22, lane);
        if (k + 3 < PAIRS_PW)
            ldpref(cur, neighbors, mask, offsets,
                   wbase + (long)(k + 3) * 192 + lane);
    }
}

extern "C" void kernel_launch(void* const* d_in, const int* in_sizes, int n_in,
                              void* d_out, int out_size, void* d_ws, size_t ws_size,
                              hipStream_t stream) {
    const float* positions = (const float*)d_in[0];
    const float* cell      = (const float*)d_in[1];
    const float* offsets   = (const float*)d_in[2];
    const float* mask      = (const float*)d_in[3];
    const int*   neighbors = (const int*)d_in[4];
    float*       out       = (float*)d_out;

    const int BN = in_sizes[0] / 3;        // B*N = 32768
    const int B  = in_sizes[1] / 9;        // 8
    const int N  = BN / B;                 // 4096

    const int rows_pb = WAVES * PAIRS_PW * 2;      // 128
    dim3 block(64 * WAVES, 1, 1);                  // 512 threads = 8 waves
    dim3 grid(BN / rows_pb, 1, 1);                 // 256 blocks, all resident
    deepmd_angular_kernel<<<grid, block, 0, stream>>>(
        positions, cell, offsets, mask, neighbors, out, N);
}

// Round 5
// 115.915 us; speedup vs baseline: 1.1570x; 1.1570x over previous
//
#include <hip/hip_runtime.h>
#include <math.h>

// Deepmd angular descriptor, f32 in / f32 out. B=8, N=4096, M=96, OUT_W=384.
//
// R20: fat-load read side, minimal diff from the 34-us R15/R16 baseline.
// Evidence: 3.3 TB/s cold-read plateau for ANY occupancy >=16 w/CU
// (R15==R16), latency-starved below (R18/R19 at 8 w/CU: 40/44 us), no
// convoy (R19: zero barriers, slower), VALU/LDS/traffic all non-binding
// (R17 counters). Surviving model: per-CU in-flight VMEM *instruction*
// queue caps read BW at depth x bytes-per-instr / latency. Copy ubench
// (6.3 TB/s) issues 1024 B/instr; our mix averaged 427 B/instr -> 3.3.
// Fix: neighbors+mask per 2-row iteration become ONE int4 + ONE float4
// (lanes 0-47, 768 B/instr) instead of 6 dword loads; offsets stay dwordx3
// (768 B/instr). 9 -> 5 VMEM/iter, 427 -> 768 B/instr. Values are moved to
// R15's proven (lane,slot) layout in-register: slot s of lane l = component
// (l&3) of source lane 16s+(l>>2): 24 shfl + ~18 cndmask per iter (~150 cy,
// negligible). Ballot-rank + register merge + b128/b64 stores byte-identical.
// Shell = R16: 512 thr, 64 KB float4 pos LDS, one __syncthreads, grid 512,
// 2 blocks/CU (LDS-capped), 16 w/CU, launch_bounds(512,4) -> VGPR cap 128
// (no spill risk; R17 measured 52 VGPR for this consume code).
#define M_NB   96
#define OUT_W  384
#define NATOM  4096
#define WPB    8                    // waves per block (512 threads)
#define ITERS  4                    // 2 rows per iteration -> 8 rows/wave
#define LOWM   0x00000000FFFFFFFFull
#define HIGHM  0xFFFFFFFF00000000ull

// fold one item (row floats [base,base+3)) into this lane's output slots:
// float4 owns [4*lane,4*lane+4), float2 owns [256+2*lane,256+2*lane+2)
__device__ __forceinline__ void merge3(float4& a4, float2& a2, int base,
                                       float v0, float v1, float v2, int lane)
{
    const int f4lo = 4 * lane;
    const int f2lo = 256 + 2 * lane;
    const float v[3] = {v0, v1, v2};
    #pragma unroll
    for (int t = 0; t < 3; ++t) {
        const int idx = base + t;
        if      (idx == f4lo)     a4.x = v[t];
        else if (idx == f4lo + 1) a4.y = v[t];
        else if (idx == f4lo + 2) a4.z = v[t];
        else if (idx == f4lo + 3) a4.w = v[t];
        else if (idx == f2lo)     a2.x = v[t];
        else if (idx == f2lo + 1) a2.y = v[t];
    }
}

__global__ __launch_bounds__(64 * WPB, 4) void deepmd_angular_kernel(
    const float* __restrict__ positions,  // [B,N,3]
    const float* __restrict__ cell,       // [B,3,3]
    const float* __restrict__ offsets,    // [B,N,M,3]
    const float* __restrict__ mask,       // [B,N,M]
    const int*   __restrict__ neighbors,  // [B,N,M]
    float*       __restrict__ out,        // [B,N,OUT_W]
    int N)
{
    __shared__ float4 pos4_s[NATOM];        // 64 KB padded position table

    const int tid  = threadIdx.x;
    const int wv   = tid >> 6;
    const int lane = tid & 63;

    const int p0 = blockIdx.x * (WPB * 2 * ITERS);   // 64 rows per block
    const int b  = p0 / N;                           // uniform (64 | N)

    // ---- stage batch positions -> LDS (padded to 16 B/atom) ----
    {
        const float* pb_ = positions + (size_t)b * N * 3;
        for (int a = tid; a < NATOM; a += 64 * WPB) {
            const float3 v = *(const float3*)(pb_ + 3 * a);
            pos4_s[a] = make_float4(v.x, v.y, v.z, 0.f);
        }
    }
    __syncthreads();                             // only barrier in the kernel

    const float* cb = cell + (size_t)b * 9;      // uniform -> scalar loads
    const float c00 = cb[0], c01 = cb[1], c02 = cb[2];
    const float c10 = cb[3], c11 = cb[4], c12 = cb[5];
    const float c20 = cb[6], c21 = cb[7], c22 = cb[8];

    const int r0 = p0 + wv * (2 * ITERS);        // wave's first row
    const int lq = lane >> 2;                    // fat-load source sublane
    const int lc = lane & 3;                     // fat-load component select

    #pragma unroll
    for (int it = 0; it < ITERS; ++it) {
        const int  q0   = r0 + it * 2;           // first of this iter's 2 rows
        const long base = (long)q0 * M_NB;       // contiguous 192 elements

        // ---- fat stream loads: 768 B/instr ----
        int4   nv = make_int4(0, 0, 0, 0);
        float4 mv = make_float4(0.f, 0.f, 0.f, 0.f);
        if (lane < 48) {                         // 192 elems = 48 int4/float4
            nv = ((const int4*)  (neighbors + base))[lane];
            mv = ((const float4*)(mask      + base))[lane];
        }
        const float3 o0 = *(const float3*)(offsets + (base + lane) * 3);
        const float3 o1 = *(const float3*)(offsets + (base + lane + 64) * 3);
        const float3 o2 = *(const float3*)(offsets + (base + lane + 128) * 3);

        // ---- redistribute to R15 layout: slot s of lane l = component
        // (l&3) of fat-load lane 16*s+(l>>2) ----
        int   j0, j1, j2;
        float m0, m1, m2;
        #pragma unroll
        for (int s = 0; s < 3; ++s) {
            const int src = 16 * s + lq;
            const int   ax = __shfl(nv.x, src), ay = __shfl(nv.y, src);
            const int   az = __shfl(nv.z, src), aw = __shfl(nv.w, src);
            const int   jl = (lc & 1) ? ay : ax;
            const int   jh = (lc & 1) ? aw : az;
            const int   jj = (lc & 2) ? jh : jl;
            const float bx = __shfl(mv.x, src), by = __shfl(mv.y, src);
            const float bz = __shfl(mv.z, src), bw = __shfl(mv.w, src);
            const float ml = (lc & 1) ? by : bx;
            const float mh = (lc & 1) ? bw : bz;
            const float mm = (lc & 2) ? mh : ml;
            if (s == 0) { j0 = jj; m0 = mm; }
            else if (s == 1) { j1 = jj; m1 = mm; }
            else { j2 = jj; m2 = mm; }
        }

        // ---- LDS gathers ----
        const int nn0 = q0 - b * N;
        const float4 pi0 = pos4_s[nn0];          // uniform broadcasts
        const float4 pi1 = pos4_s[nn0 + 1];
        const float4 pj0 = pos4_s[j0];
        const float4 pj1 = pos4_s[j1];
        const float4 pj2 = pos4_s[j2];
        const float4 pa  = (lane < 32) ? pi0 : pi1;   // item1's own atom

        // ---- cut per item (w = cut * dis_vec stored in-place) ----
        float w0x = pj0.x - pi0.x + o0.x * c00 + o0.y * c10 + o0.z * c20;
        float w0y = pj0.y - pi0.y + o0.x * c01 + o0.y * c11 + o0.z * c21;
        float w0z = pj0.z - pi0.z + o0.x * c02 + o0.y * c12 + o0.z * c22;
        float d   = sqrtf(w0x * w0x + w0y * w0y + w0z * w0z + 1e-12f);
        float c0v = 0.f;
        if (m0 != 0.f && d < 6.f)
            c0v = 0.5f * (__cosf(d * 0.52359877559829887f) + 1.f) / d;
        w0x *= c0v; w0y *= c0v; w0z *= c0v;

        float w1x = pj1.x - pa.x + o1.x * c00 + o1.y * c10 + o1.z * c20;
        float w1y = pj1.y - pa.y + o1.x * c01 + o1.y * c11 + o1.z * c21;
        float w1z = pj1.z - pa.z + o1.x * c02 + o1.y * c12 + o1.z * c22;
        d = sqrtf(w1x * w1x + w1y * w1y + w1z * w1z + 1e-12f);
        float c1v = 0.f;
        if (m1 != 0.f && d < 6.f)
            c1v = 0.5f * (__cosf(d * 0.52359877559829887f) + 1.f) / d;
        w1x *= c1v; w1y *= c1v; w1z *= c1v;

        float w2x = pj2.x - pi1.x + o2.x * c00 + o2.y * c10 + o2.z * c20;
        float w2y = pj2.y - pi1.y + o2.x * c01 + o2.y * c11 + o2.z * c21;
        float w2z = pj2.z - pi1.z + o2.x * c02 + o2.y * c12 + o2.z * c22;
        d = sqrtf(w2x * w2x + w2y * w2y + w2z * w2z + 1e-12f);
        float c2v = 0.f;
        if (m2 != 0.f && d < 6.f)
            c2v = 0.5f * (__cosf(d * 0.52359877559829887f) + 1.f) / d;
        w2x *= c2v; w2y *= c2v; w2z *= c2v;

        // ---- row0: rank + register merge ----
        // rank(m) = #{k: cut_k > cut_m} + #{k<m: cut_k == cut_m}
        float4 a4 = make_float4(0.f, 0.f, 0.f, 0.f);
        float2 a2 = make_float2(0.f, 0.f);
        unsigned long long t = __ballot(c0v != 0.f);
        while (t) {                                  // item m = s (c0 owner)
            const int s = (int)__builtin_ctzll(t); t &= t - 1;
            const float c = __shfl(c0v, s);
            const int rank = __popcll(__ballot(c0v > c))
                           + __popcll(__ballot(c1v > c) & LOWM)
                           + __popcll(__ballot(c0v == c) & ((1ull << s) - 1ull));
            merge3(a4, a2, 3 * rank,
                   __shfl(w0x, s), __shfl(w0y, s), __shfl(w0z, s), lane);
        }
        t = __ballot(c1v != 0.f) & LOWM;
        while (t) {                                  // item m = 64+s (c1 low)
            const int s = (int)__builtin_ctzll(t); t &= t - 1;
            const float c = __shfl(c1v, s);
            const int rank = __popcll(__ballot(c0v > c))
                           + __popcll(__ballot(c1v > c) & LOWM)
                           + __popcll(__ballot(c0v == c))
                           + __popcll(__ballot(c1v == c) & LOWM & ((1ull << s) - 1ull));
            merge3(a4, a2, 3 * rank,
                   __shfl(w1x, s), __shfl(w1y, s), __shfl(w1z, s), lane);
        }
        float* row0 = out + (size_t)q0 * OUT_W;
        ((float4*)row0)[lane] = a4;
        ((float2*)(row0 + 256))[lane] = a2;

        // ---- row1: rank + register merge ----
        float4 b4 = make_float4(0.f, 0.f, 0.f, 0.f);
        float2 b2 = make_float2(0.f, 0.f);
        t = __ballot(c1v != 0.f) & HIGHM;
        while (t) {                                  // item m = s-32 (c1 high)
            const int s = (int)__builtin_ctzll(t); t &= t - 1;
            const float c = __shfl(c1v, s);
            const int rank = __popcll(__ballot(c1v > c) & HIGHM)
                           + __popcll(__ballot(c2v > c))
                           + __popcll(__ballot(c1v == c) & HIGHM & ((1ull << s) - 1ull));
            merge3(b4, b2, 3 * rank,
                   __shfl(w1x, s), __shfl(w1y, s), __shfl(w1z, s), lane);
        }
        t = __ballot(c2v != 0.f);
        while (t) {                                  // item m = 32+s (c2 owner)
            const int s = (int)__builtin_ctzll(t); t &= t - 1;
            const float c = __shfl(c2v, s);
            const int rank = __popcll(__ballot(c1v > c) & HIGHM)
                           + __popcll(__ballot(c2v > c))
                           + __popcll(__ballot(c1v == c) & HIGHM)
                           + __popcll(__ballot(c2v == c) & ((1ull << s) - 1ull));
            merge3(b4, b2, 3 * rank,
                   __shfl(w2x, s), __shfl(w2y, s), __shfl(w2z, s), lane);
        }
        float* row1 = out + (size_t)(q0 + 1) * OUT_W;
        ((float4*)row1)[lane] = b4;
        ((float2*)(row1 + 256))[lane] = b2;
    }
}

extern "C" void kernel_launch(void* const* d_in, const int* in_sizes, int n_in,
                              void* d_out, int out_size, void* d_ws, size_t ws_size,
                              hipStream_t stream) {
    const float* positions = (const float*)d_in[0];
    const float* cell      = (const float*)d_in[1];
    const float* offsets   = (const float*)d_in[2];
    const float* mask      = (const float*)d_in[3];
    const int*   neighbors = (const int*)d_in[4];
    float*       out       = (float*)d_out;

    const int BN = in_sizes[0] / 3;        // B*N = 32768
    const int B  = in_sizes[1] / 9;        // 8
    const int N  = BN / B;                 // 4096

    dim3 block(64 * WPB, 1, 1);                // 512 threads = 8 waves
    dim3 grid(BN / (WPB * 2 * ITERS), 1, 1);   // 512 blocks = 2/CU resident
    deepmd_angular_kernel<<<grid, block, 0, stream>>>(
        positions, cell, offsets, mask, neighbors, out, N);
}